// Round 9
// baseline (38.800 us; speedup 1.0000x reference)
//
#include <hip/hip_runtime.h>

// WOMD post-processing v9: ZERO DS-pipe ops (no LDS, no shuffles).
// Cross-lane via DPP (VALU) + v_readlane + ballot/ffs. Within-mask computed
// on the fly for the 6 picked rows only (d^2 < t^2 == sqrtf(d^2) < t exactly,
// since t in {2.5,1,2} and t^2 are exactly representable). MPA tail runs
// redundantly on all lanes, registers only, literal indices (v4's proven form).

#define NSC 64
#define NAG 64
#define NJF 32
#define NSTEP 80
#define KP 6
#define TOUT 16

struct F3 { float x, y, z; };

__device__ __forceinline__ int   fasi(float f) { return __builtin_bit_cast(int, f); }
__device__ __forceinline__ float asif(int i)   { return __builtin_bit_cast(float, i); }

// After these, lane31 holds the reduction of lanes 0..31 and lane63 of 32..63.
// row_shr:k = 0x110|k, row_bcast15 = 0x142 (gfx9 DPP, VALU pipe — no DS).
__device__ __forceinline__ float dppmax32(float v) {
    v = fmaxf(v, asif(__builtin_amdgcn_update_dpp(fasi(v), fasi(v), 0x111, 0xf, 0xf, false)));
    v = fmaxf(v, asif(__builtin_amdgcn_update_dpp(fasi(v), fasi(v), 0x112, 0xf, 0xf, false)));
    v = fmaxf(v, asif(__builtin_amdgcn_update_dpp(fasi(v), fasi(v), 0x114, 0xf, 0xf, false)));
    v = fmaxf(v, asif(__builtin_amdgcn_update_dpp(fasi(v), fasi(v), 0x118, 0xf, 0xf, false)));
    v = fmaxf(v, asif(__builtin_amdgcn_update_dpp(fasi(v), fasi(v), 0x142, 0xf, 0xf, false)));
    return v;
}
__device__ __forceinline__ float dppsum32(float v) {
    v += asif(__builtin_amdgcn_update_dpp(0, fasi(v), 0x111, 0xf, 0xf, true));
    v += asif(__builtin_amdgcn_update_dpp(0, fasi(v), 0x112, 0xf, 0xf, true));
    v += asif(__builtin_amdgcn_update_dpp(0, fasi(v), 0x114, 0xf, 0xf, true));
    v += asif(__builtin_amdgcn_update_dpp(0, fasi(v), 0x118, 0xf, 0xf, true));
    v += asif(__builtin_amdgcn_update_dpp(0, fasi(v), 0x142, 0xf, 0xf, true));
    return v;
}
// broadcast the per-half reduction (lanes 31/63) to every lane of its half
__device__ __forceinline__ float bcast_half(float v, int half) {
    int va = __builtin_amdgcn_readlane(fasi(v), 31);
    int vb = __builtin_amdgcn_readlane(fasi(v), 63);
    return asif(half ? vb : va);
}

__global__ __launch_bounds__(64)
void womd_pp9(const float* __restrict__ ag_type,
              const float* __restrict__ trajs,
              const float* __restrict__ scores,
              float* __restrict__ out)
{
    const int tid  = threadIdx.x;
    const int half = tid >> 5;          // agent of the pair
    const int hl   = tid & 31;          // mode index within 32-group
    const int s    = blockIdx.x >> 5;   // scene
    const int p    = blockIdx.x & 31;   // agent-pair
    const int a    = p * 2 + half;      // agent

    // ---- loads ----
    float raw = scores[((size_t)s * NJF + hl) * NAG + a];
    size_t eoff = (((size_t)(s * NJF + hl) * NAG + a) * NSTEP + (NSTEP - 1)) * 3;
    float exx = trajs[eoff];
    float exy = trajs[eoff + 1];
    const float* at = ag_type + (size_t)(s * NAG + a) * 3;
    const float thresh = at[0] * 2.5f + at[1] * 1.0f + at[2] * 2.0f;
    const float th2 = thresh * thresh;   // 6.25 / 1 / 4 — exact

    // ---- softmax over 32 modes (DPP + readlane, no DS) ----
    float mx = bcast_half(dppmax32(raw), half);
    float ev = expf(raw - mx);
    float sum = bcast_half(dppsum32(ev), half);
    float sm = ev / sum;

    // ---- MTR NMS: 6 picks. DPP max + ballot/ffs (first-index tie-break).
    // within(pick, hl) computed on the fly: d^2 < t^2  ==  sqrtf(d^2) < t.
    int   sel[KP];                       // literal-indexed only
    float sx[KP], sy[KP], sk[KP];        // picked endpoint/score (all lanes)
    float ls = sm;
    #pragma unroll
    for (int k = 0; k < KP; ++k) {
        float v  = dppmax32(ls);
        float gm = bcast_half(v, half);
        unsigned long long bal = __ballot(ls == gm);
        int idxA = __ffs((unsigned)bal) - 1;          // uniform (SGPR)
        int idxB = __ffs((unsigned)(bal >> 32)) - 1;  // uniform (SGPR)
        int myidx = half ? idxB : idxA;
        sel[k] = myidx;

        float pxA = asif(__builtin_amdgcn_readlane(fasi(exx), idxA));
        float pxB = asif(__builtin_amdgcn_readlane(fasi(exx), idxB + 32));
        float pyA = asif(__builtin_amdgcn_readlane(fasi(exy), idxA));
        float pyB = asif(__builtin_amdgcn_readlane(fasi(exy), idxB + 32));
        float skA = asif(__builtin_amdgcn_readlane(fasi(sm),  idxA));
        float skB = asif(__builtin_amdgcn_readlane(fasi(sm),  idxB + 32));
        float px = half ? pxB : pxA;
        float py = half ? pyB : pyA;
        sx[k] = px;  sy[k] = py;  sk[k] = half ? skB : skA;

        float dx = exx - px, dy = exy - py;
        bool w = (dx * dx + dy * dy) < th2;
        ls *= w ? 0.01f : 1.0f;          // 0.99f+0.01f == 1.0f
        ls  = (hl == myidx) ? -1.0f : ls;
    }

    // ---- trajectory gather: issue loads NOW (overlap the tail) ----
    F3 pt[3];
    #pragma unroll
    for (int i = 0; i < 3; ++i) {
        int sj = (hl & 16) ? sel[2 * i + 1] : sel[2 * i];  // mode (hl>>4)+2i
        int t  = hl & 15;
        size_t src = (((size_t)(s * NJF + sj) * NAG + a) * NSTEP + (4 + 5 * t)) * 3;
        pt[i] = *(const F3*)(trajs + src);
    }

    // ---- MPA tail: all lanes redundant, registers only (v4's proven form) ----
    float ssum = 0.f;
    #pragma unroll
    for (int k = 0; k < KP; ++k) ssum += sk[k];
    float sk0[KP];
    #pragma unroll
    for (int k = 0; k < KP; ++k) { sk[k] /= ssum; sk0[k] = sk[k]; }

    unsigned w2[KP];
    #pragma unroll
    for (int i = 0; i < KP; ++i) {
        unsigned r = 0;
        #pragma unroll
        for (int j = 0; j < KP; ++j) {
            float dx = sx[i] - sx[j], dy = sy[i] - sy[j];
            r |= ((dx * dx + dy * dy) < th2) ? (1u << j) : 0u;
        }
        w2[i] = r;
    }

    // stable descending rank from the original normalized scores
    int rank[KP];
    #pragma unroll
    for (int j = 0; j < KP; ++j) {
        int r = 0;
        #pragma unroll
        for (int i = 0; i < KP; ++i)
            r += ((sk0[i] > sk0[j]) || (sk0[i] == sk0[j] && i < j)) ? 1 : 0;
        rank[j] = r;
    }

    // sequential MPA scan in rank order (select chains, literal idx only)
    #pragma unroll
    for (int t = 0; t < KP; ++t) {
        float sk_k = sk[0]; unsigned w2k = w2[0];
        #pragma unroll
        for (int j = 1; j < KP; ++j) {
            bool is = (rank[j] == t);
            sk_k = is ? sk[j] : sk_k;
            w2k  = is ? w2[j] : w2k;
        }
        bool any = false;
        #pragma unroll
        for (int j = 0; j < KP; ++j)
            any = any || ((((w2k >> j) & 1u) != 0u) && (sk[j] > sk_k));
        #pragma unroll
        for (int j = 0; j < KP; ++j)
            if (rank[j] == t && any) sk[j] = 0.001f;
    }

    // normalize; softmax(log p / 0.5) == p^2 / sum(p^2)
    float s2 = 0.f;
    #pragma unroll
    for (int k = 0; k < KP; ++k) s2 += sk[k];
    #pragma unroll
    for (int k = 0; k < KP; ++k) sk[k] /= s2;
    float q[KP]; float s3 = 0.f;
    #pragma unroll
    for (int k = 0; k < KP; ++k) { q[k] = sk[k] * sk[k]; s3 += q[k]; }

    // ---- score store: lanes 0-5 of each half, select-chain (no runtime idx) ----
    float qs = q[0] / s3;
    qs = (hl == 1) ? q[1] / s3 : qs;
    qs = (hl == 2) ? q[2] / s3 : qs;
    qs = (hl == 3) ? q[3] / s3 : qs;
    qs = (hl == 4) ? q[4] / s3 : qs;
    qs = (hl == 5) ? q[5] / s3 : qs;
    const size_t SCBASE = (size_t)NSC * NAG * KP * TOUT * 3;
    if (hl < KP) out[SCBASE + ((size_t)s * NAG + a) * KP + hl] = qs;

    // ---- trajectory stores ----
    size_t ob = ((size_t)s * NAG + a) * (KP * TOUT * 3);
    #pragma unroll
    for (int i = 0; i < 3; ++i)
        *(F3*)(out + ob + (size_t)(hl + 32 * i) * 3) = pt[i];
}

extern "C" void kernel_launch(void* const* d_in, const int* in_sizes, int n_in,
                              void* d_out, int out_size, void* d_ws, size_t ws_size,
                              hipStream_t stream) {
    const float* ag_type = (const float*)d_in[0];
    const float* trajs   = (const float*)d_in[1];
    const float* scores  = (const float*)d_in[2];
    float* out = (float*)d_out;

    womd_pp9<<<NSC * (NAG / 2), 64, 0, stream>>>(ag_type, trajs, scores, out);
}

// Round 10
// 28.352 us; speedup vs baseline: 1.3685x; 1.3685x over previous
//
#include <hip/hip_runtime.h>

// WOMD post-processing v10: 4 agents per wave (16 lanes/agent, 2 modes/lane),
// 1024 waves total (half of v2). Zero LDS. Within-mask computed on the fly
// per pick (sqrtf(d^2)<thresh, identical FP to v2). Argmax: value butterfly +
// 2 ballots + ffs (mode 0-15 mask preferred -> exact jnp.argmax tie-break).
// Tests the surviving model: time ~ waves x stream (v7 proved the 2x-up
// direction; this is the 0.5x-down direction).

#define NSC 64
#define NAG 64
#define NJF 32
#define NSTEP 80
#define KP 6
#define TOUT 16

struct F3 { float x, y, z; };

__global__ __launch_bounds__(64)
void womd_pp10(const float* __restrict__ ag_type,
               const float* __restrict__ trajs,
               const float* __restrict__ scores,
               float* __restrict__ out)
{
    const int tid = threadIdx.x;
    const int g   = tid >> 4;              // group 0..3 = agent slot
    const int gl  = tid & 15;              // lane within group
    const int ga  = blockIdx.x * 4 + g;    // global agent 0..4095
    const int s   = ga >> 6;               // scene
    const int a   = ga & 63;               // agent

    // modes owned by this lane: j0 = gl, j1 = gl + 16
    // ---- loads ----
    const float* sp = scores + (size_t)s * NJF * NAG + a;
    float raw0 = sp[(size_t)gl * NAG];
    float raw1 = sp[(size_t)(gl + 16) * NAG];

    const float* tb = trajs + (size_t)s * NJF * NAG * NSTEP * 3;  // scene base
    size_t e0 = (((size_t)gl * NAG + a) * NSTEP + (NSTEP - 1)) * 3;
    size_t e1 = (((size_t)(gl + 16) * NAG + a) * NSTEP + (NSTEP - 1)) * 3;
    float2 p0 = *(const float2*)(tb + e0);     // endpoint of mode j0
    float2 p1 = *(const float2*)(tb + e1);     // endpoint of mode j1

    F3 atv = *(const F3*)(ag_type + (size_t)(s * NAG + a) * 3);
    const float thresh = atv.x * 2.5f + atv.y * 1.0f + atv.z * 2.0f;

    // ---- softmax over 32 modes (16-lane butterfly, 2 modes/lane) ----
    float mx = fmaxf(raw0, raw1);
    #pragma unroll
    for (int off = 8; off > 0; off >>= 1)
        mx = fmaxf(mx, __shfl_xor(mx, off, 16));
    float ev0 = expf(raw0 - mx);
    float ev1 = expf(raw1 - mx);
    float sum = ev0 + ev1;
    #pragma unroll
    for (int off = 8; off > 0; off >>= 1)
        sum += __shfl_xor(sum, off, 16);
    float sm0 = ev0 / sum;
    float sm1 = ev1 / sum;

    // ---- MTR NMS: 6 picks ----
    int   sel[KP];
    float skp[KP], sxp[KP], syp[KP];       // pick score/endpoint (all lanes)
    float ls0 = sm0, ls1 = sm1;
    #pragma unroll
    for (int k = 0; k < KP; ++k) {
        float v = fmaxf(ls0, ls1);
        #pragma unroll
        for (int off = 8; off > 0; off >>= 1)
            v = fmaxf(v, __shfl_xor(v, off, 16));
        // first mode index attaining the max (modes 0-15 before 16-31)
        unsigned long long b0 = __ballot(ls0 == v);
        unsigned long long b1 = __ballot(ls1 == v);
        unsigned m0 = (unsigned)(b0 >> (g * 16)) & 0xFFFFu;
        unsigned m1 = (unsigned)(b1 >> (g * 16)) & 0xFFFFu;
        int idx = m0 ? (__ffs(m0) - 1) : (16 + __ffs(m1) - 1);
        sel[k] = idx;

        // pick endpoint+score broadcast: source-side select, 3 shuffles
        int  il = idx & 15;
        bool lo = (idx < 16);
        float sxv = lo ? p0.x : p1.x;
        float syv = lo ? p0.y : p1.y;
        float skv = lo ? sm0 : sm1;
        float px = __shfl(sxv, il, 16);
        float py = __shfl(syv, il, 16);
        float pk = __shfl(skv, il, 16);
        sxp[k] = px;  syp[k] = py;  skp[k] = pk;

        // within(pick, my modes): identical FP to v2 (sqrtf, strict <)
        float dx0 = p0.x - px, dy0 = p0.y - py;
        float dx1 = p1.x - px, dy1 = p1.y - py;
        bool w0 = sqrtf(dx0 * dx0 + dy0 * dy0) < thresh;
        bool w1 = sqrtf(dx1 * dx1 + dy1 * dy1) < thresh;
        ls0 *= w0 ? 0.01f : 1.0f;          // 0.99f+0.01f == 1.0f
        ls1 *= w1 ? 0.01f : 1.0f;
        ls0 = (gl == idx)      ? -1.0f : ls0;
        ls1 = (gl + 16 == idx) ? -1.0f : ls1;
    }

    // ---- trajectory gather: t = gl for all 6 modes; issue before tail ----
    F3 pt[KP];
    #pragma unroll
    for (int i = 0; i < KP; ++i) {
        size_t src = (((size_t)sel[i] * NAG + a) * NSTEP + (4 + 5 * gl)) * 3;
        pt[i] = *(const F3*)(tb + src);
    }

    // ---- MPA tail: redundant on all 16 lanes, registers only ----
    float ssum = 0.f;
    #pragma unroll
    for (int k = 0; k < KP; ++k) ssum += skp[k];
    float sk[KP], sk0[KP];
    #pragma unroll
    for (int k = 0; k < KP; ++k) { sk[k] = skp[k] / ssum; sk0[k] = sk[k]; }

    unsigned w2[KP];
    #pragma unroll
    for (int i = 0; i < KP; ++i) {
        unsigned r = 0;
        #pragma unroll
        for (int j = 0; j < KP; ++j) {
            float dx = sxp[i] - sxp[j], dy = syp[i] - syp[j];
            r |= (sqrtf(dx * dx + dy * dy) < thresh) ? (1u << j) : 0u;
        }
        w2[i] = r;
    }

    // stable descending rank (ties -> lower index)
    int rank[KP];
    #pragma unroll
    for (int j = 0; j < KP; ++j) {
        int r = 0;
        #pragma unroll
        for (int i = 0; i < KP; ++i)
            r += ((sk0[i] > sk0[j]) || (sk0[i] == sk0[j] && i < j)) ? 1 : 0;
        rank[j] = r;
    }

    // sequential MPA scan in rank order (select chains, literal idx only)
    #pragma unroll
    for (int t = 0; t < KP; ++t) {
        float sk_k = sk[0]; unsigned w2k = w2[0];
        #pragma unroll
        for (int j = 1; j < KP; ++j) {
            bool is = (rank[j] == t);
            sk_k = is ? sk[j] : sk_k;
            w2k  = is ? w2[j] : w2k;
        }
        bool any = false;
        #pragma unroll
        for (int j = 0; j < KP; ++j)
            any = any || ((((w2k >> j) & 1u) != 0u) && (sk[j] > sk_k));
        #pragma unroll
        for (int j = 0; j < KP; ++j)
            if (rank[j] == t && any) sk[j] = 0.001f;
    }

    // normalize; softmax(log p / 0.5) == p^2 / sum(p^2)
    float s2 = 0.f;
    #pragma unroll
    for (int k = 0; k < KP; ++k) s2 += sk[k];
    #pragma unroll
    for (int k = 0; k < KP; ++k) sk[k] /= s2;
    float q[KP]; float s3 = 0.f;
    #pragma unroll
    for (int k = 0; k < KP; ++k) { q[k] = sk[k] * sk[k]; s3 += q[k]; }

    // ---- score store: lanes 0-5 of each group, select chain ----
    float qs = q[0] / s3;
    qs = (gl == 1) ? q[1] / s3 : qs;
    qs = (gl == 2) ? q[2] / s3 : qs;
    qs = (gl == 3) ? q[3] / s3 : qs;
    qs = (gl == 4) ? q[4] / s3 : qs;
    qs = (gl == 5) ? q[5] / s3 : qs;
    const size_t SCBASE = (size_t)NSC * NAG * KP * TOUT * 3;
    if (gl < KP) out[SCBASE + (size_t)ga * KP + gl] = qs;

    // ---- trajectory stores: e = 16*i + gl (mode i, step gl) ----
    size_t ob = (size_t)ga * (KP * TOUT * 3);
    #pragma unroll
    for (int i = 0; i < KP; ++i)
        *(F3*)(out + ob + (size_t)(16 * i + gl) * 3) = pt[i];
}

extern "C" void kernel_launch(void* const* d_in, const int* in_sizes, int n_in,
                              void* d_out, int out_size, void* d_ws, size_t ws_size,
                              hipStream_t stream) {
    const float* ag_type = (const float*)d_in[0];
    const float* trajs   = (const float*)d_in[1];
    const float* scores  = (const float*)d_in[2];
    float* out = (float*)d_out;

    womd_pp10<<<NSC * NAG / 4, 64, 0, stream>>>(ag_type, trajs, scores, out);
}